// Round 3
// baseline (1141.569 us; speedup 1.0000x reference)
//
#include <hip/hip_runtime.h>

typedef __bf16 bf16;
typedef bf16 bf16x8 __attribute__((ext_vector_type(8)));
typedef float f32x4 __attribute__((ext_vector_type(4)));
typedef unsigned int u32;
typedef unsigned short u16;

#define BB 4
#define SS 4096
#define DD 1024
#define EE 64
static constexpr float SCALE2 = 0.18033688011112042f; // (1/8)*log2(e)
static constexpr float MFIX = 16.0f;                  // fixed softmax shift (log2 domain)

#define MFMA(a,b,c) __builtin_amdgcn_mfma_f32_16x16x32_bf16((a),(b),(c),0,0,0)

typedef __attribute__((address_space(3))) unsigned int lds_u32;
typedef const __attribute__((address_space(1))) unsigned int glb_u32;

static __device__ __forceinline__ void gload16(const void* g, void* l) {
    __builtin_amdgcn_global_load_lds((glb_u32*)g, (lds_u32*)l, 16, 0, 0);
}

static __device__ __forceinline__ u16 f2bf(float x) {
    union { float f; u32 u; } v; v.f = x;
    u32 r = v.u + 0x7FFFu + ((v.u >> 16) & 1u);
    return (u16)(r >> 16);
}
static __device__ __forceinline__ u32 pk2(float a, float b) {
    return (u32)f2bf(a) | ((u32)f2bf(b) << 16);
}
static __device__ __forceinline__ float fexp2(float x) {
    return __builtin_amdgcn_exp2f(x);
}

// ---------------- Kernel 1: Q/K projection GEMM (fp32 in -> bf16 out), sw-prefetch ----
__global__ __launch_bounds__(512, 4) void k_proj(const float* __restrict__ enc,
                                                 const float* __restrict__ wq,
                                                 const float* __restrict__ wk,
                                                 u16* __restrict__ qout,
                                                 u16* __restrict__ kout) {
    __shared__ __align__(16) u16 la[128 * 64];
    __shared__ __align__(16) u16 lw[64 * 64];
    const int tid = threadIdx.x;
    const int half = blockIdx.x & 1;
    const int m0 = (blockIdx.x >> 1) * 128;
    const int w = tid >> 6, lane = tid & 63, l15 = lane & 15, quad = lane >> 4;
    const int ari = tid >> 2, ac0 = (tid & 3) << 4;   // A staging: 128 rows x 16 floats
    const int wri = tid >> 3, wc0 = (tid & 7) << 3;   // W staging: 64 rows x 8 floats
    const float* arow = enc + (size_t)(m0 + ari) * DD + ac0;
    const float* wrow = (half ? wk : wq) + (size_t)wri * DD + wc0;
    u16* dst = half ? kout : qout;

    float4 a0 = *(const float4*)(arow);
    float4 a1 = *(const float4*)(arow + 4);
    float4 a2 = *(const float4*)(arow + 8);
    float4 a3 = *(const float4*)(arow + 12);
    float4 b0 = *(const float4*)(wrow);
    float4 b1 = *(const float4*)(wrow + 4);

    f32x4 acc[4];
#pragma unroll
    for (int i = 0; i < 4; i++) acc[i] = f32x4{0.f, 0.f, 0.f, 0.f};

    for (int kk = 0; kk < DD; kk += 64) {
        uint4 pa0, pa1, pw;
        pa0.x = pk2(a0.x, a0.y); pa0.y = pk2(a0.z, a0.w);
        pa0.z = pk2(a1.x, a1.y); pa0.w = pk2(a1.z, a1.w);
        pa1.x = pk2(a2.x, a2.y); pa1.y = pk2(a2.z, a2.w);
        pa1.z = pk2(a3.x, a3.y); pa1.w = pk2(a3.z, a3.w);
        pw.x = pk2(b0.x, b0.y); pw.y = pk2(b0.z, b0.w);
        pw.z = pk2(b1.x, b1.y); pw.w = pk2(b1.z, b1.w);
        __syncthreads();   // prev iteration's readers done
        int ag = ac0 >> 3;
        *(uint4*)&la[ari * 64 + ((ag + 0) ^ (ari & 7)) * 8] = pa0;
        *(uint4*)&la[ari * 64 + ((ag + 1) ^ (ari & 7)) * 8] = pa1;
        *(uint4*)&lw[wri * 64 + (((wc0 >> 3) ^ (wri & 7))) * 8] = pw;
        __syncthreads();
        if (kk + 64 < DD) {   // prefetch next tile behind MFMA
            a0 = *(const float4*)(arow + kk + 64);
            a1 = *(const float4*)(arow + kk + 68);
            a2 = *(const float4*)(arow + kk + 72);
            a3 = *(const float4*)(arow + kk + 76);
            b0 = *(const float4*)(wrow + kk + 64);
            b1 = *(const float4*)(wrow + kk + 68);
        }
        int m = 16 * w + l15;
#pragma unroll
        for (int es = 0; es < 2; es++) {
            bf16x8 af = *(const bf16x8*)&la[m * 64 + ((((es << 2) + quad) ^ (m & 7))) * 8];
#pragma unroll
            for (int ct = 0; ct < 4; ct++) {
                int n = 16 * ct + l15;
                bf16x8 bf_ = *(const bf16x8*)&lw[n * 64 + ((((es << 2) + quad) ^ (n & 7))) * 8];
                acc[ct] = MFMA(af, bf_, acc[ct]);
            }
        }
    }
#pragma unroll
    for (int ct = 0; ct < 4; ct++) {
        int col = 16 * ct + l15;
#pragma unroll
        for (int r = 0; r < 4; r++) {
            int grow = m0 + 16 * w + 4 * quad + r;
            dst[(size_t)grow * EE + col] = f2bf(acc[ct][r]);
        }
    }
}

// ---------------- Kernel 2: transpose-cast enc -> Vt[b][d][s] bf16 (conflict-free) ----
__global__ __launch_bounds__(256) void k_tcast(const float* __restrict__ enc, u16* __restrict__ vt) {
    __shared__ u32 lt2[32][67];
    const int tid = threadIdx.x;
    const int dt = blockIdx.x, st = blockIdx.y, b = blockIdx.z;
    const int srow = tid >> 2, d0 = (tid & 3) << 4;
    const float* src = enc + ((size_t)(b * SS + st * 64 + srow) * DD) + dt * 64 + d0;
    float4 f0 = ((const float4*)src)[0];
    float4 f1 = ((const float4*)src)[1];
    float4 f2 = ((const float4*)src)[2];
    float4 f3 = ((const float4*)src)[3];
    float v[16];
    v[0] = f0.x; v[1] = f0.y; v[2] = f0.z; v[3] = f0.w;
    v[4] = f1.x; v[5] = f1.y; v[6] = f1.z; v[7] = f1.w;
    v[8] = f2.x; v[9] = f2.y; v[10] = f2.z; v[11] = f2.w;
    v[12] = f3.x; v[13] = f3.y; v[14] = f3.z; v[15] = f3.w;
#pragma unroll
    for (int j = 0; j < 8; j++) lt2[(d0 >> 1) + j][srow] = pk2(v[2 * j], v[2 * j + 1]);
    __syncthreads();
    const int dp = tid >> 3, soct = tid & 7;
    u32 a[8];
#pragma unroll
    for (int j = 0; j < 8; j++) a[j] = lt2[dp][soct * 8 + j];
    uint4 r0, r1;
    r0.x = (a[0] & 0xffffu) | (a[1] << 16);
    r0.y = (a[2] & 0xffffu) | (a[3] << 16);
    r0.z = (a[4] & 0xffffu) | (a[5] << 16);
    r0.w = (a[6] & 0xffffu) | (a[7] << 16);
    r1.x = (a[0] >> 16) | (a[1] & 0xffff0000u);
    r1.y = (a[2] >> 16) | (a[3] & 0xffff0000u);
    r1.z = (a[4] >> 16) | (a[5] & 0xffff0000u);
    r1.w = (a[6] >> 16) | (a[7] & 0xffff0000u);
    u16* dst0 = vt + ((size_t)(b * DD + dt * 64 + 2 * dp) * SS) + st * 64 + soct * 8;
    *(uint4*)dst0 = r0;
    *(uint4*)(dst0 + SS) = r1;
}

// ---------------- Kernel 3: fused attention q256 x d128, 2-barrier dbuf pipeline ------
// LDS map (u16 units): [0,16384)   lp (256q x 64k)  -- aliased as lq at start, lsum at end
//                      [16384 + buf*12288): lk 64x64, then lv 128x64   (buf = 0/1)
__global__ __launch_bounds__(512, 4) void k_attn(const u16* __restrict__ qg, const u16* __restrict__ kg,
                                                 const u16* __restrict__ vt, float* __restrict__ out) {
    __shared__ __align__(16) u16 lds[40960];   // 80 KB exactly -> 2 blocks/CU
    u16* lp = lds;
    float* lsum = (float*)lds;
    const int tid = threadIdx.x;
    const int w = tid >> 6, lane = tid & 63, l15 = lane & 15, quad = lane >> 4;
    const int n = blockIdx.x;
    // qt in low 4 bits, interleaved 15,0,14,1,... so contiguous block pairs sum to 68 iters
    const int i4 = n & 15;
    const int qt = (i4 & 1) ? (i4 >> 1) : (15 - (i4 >> 1));
    const int combo = n >> 4;
    const int ds = combo & 7, b = combo >> 3;
    const int q0 = qt * 256, d0 = ds * 128;
    const int kr = w & 1, qc = w >> 1;   // pass A: 2 k-halves x 4 q-slices(64)
    const int dc = w & 1, qr = w >> 1;   // pass B: 2 d-slices(64) x 4 q-slices(64)
    const int KT = 4 * qt + 4;
    const u16* qbase = qg + ((size_t)b * SS + q0) * EE;
    const u16* kbase = kg + (size_t)b * SS * EE;
    const u16* vbase = vt + ((size_t)b * DD + d0) * SS;

    // stage Q (32KB -> lp region) and K/V tile 0 (buf 0)
#pragma unroll
    for (int i = 0; i < 4; i++) {
        int goff = i * 512 + tid, grow = goff >> 3, glog = (goff & 7) ^ (grow & 7);
        gload16(qbase + (size_t)grow * EE + glog * 8, (void*)&lds[goff * 8]);
    }
    {
        int goff = tid, grow = goff >> 3, glog = (goff & 7) ^ (grow & 7);
        gload16(kbase + (size_t)grow * EE + glog * 8, (void*)&lds[16384 + goff * 8]);
#pragma unroll
        for (int i = 0; i < 2; i++) {
            int go = i * 512 + tid, gr = go >> 3, gl = (go & 7) ^ (gr & 7);
            gload16(vbase + (size_t)gr * SS + gl * 8, (void*)&lds[16384 + 4096 + go * 8]);
        }
    }
    __syncthreads();
    bf16x8 qf[4][2];
#pragma unroll
    for (int ct = 0; ct < 4; ct++) {
        int q = qc * 64 + ct * 16 + l15;
#pragma unroll
        for (int es = 0; es < 2; es++)
            qf[ct][es] = *(const bf16x8*)&lds[q * 64 + ((((es << 2) + quad) ^ (q & 7))) * 8];
    }
    __syncthreads();   // all qf reads done before lp is overwritten

    f32x4 o[4][4];
#pragma unroll
    for (int i = 0; i < 4; i++)
#pragma unroll
        for (int j = 0; j < 4; j++) o[i][j] = f32x4{0.f, 0.f, 0.f, 0.f};
    float rl[4] = {0.f, 0.f, 0.f, 0.f};

    for (int kt = 0; kt < KT; kt++) {
        const int k0 = kt * 64;
        const u16* lk = &lds[16384 + (kt & 1) * 12288];
        const u16* lv = lk + 4096;
        const bool dg = (kt >= KT - 4);
        // ---- pass A: S^T tile (64k x 256q), exp2, write P to lp ----
#pragma unroll
        for (int rt = 0; rt < 2; rt++) {
            int m = 32 * kr + 16 * rt + l15;
            bf16x8 ka0 = *(const bf16x8*)&lk[m * 64 + ((quad ^ (m & 7))) * 8];
            bf16x8 ka1 = *(const bf16x8*)&lk[m * 64 + (((4 + quad) ^ (m & 7))) * 8];
#pragma unroll
            for (int ct = 0; ct < 4; ct++) {
                f32x4 c = f32x4{0.f, 0.f, 0.f, 0.f};
                c = MFMA(ka0, qf[ct][0], c);
                c = MFMA(ka1, qf[ct][1], c);
                int qv = qc * 64 + ct * 16 + l15;
                float p[4];
#pragma unroll
                for (int r = 0; r < 4; r++) {
                    float arg = __builtin_fmaf(c[r], SCALE2, -MFIX);
                    if (dg) {
                        int kp = k0 + 32 * kr + 16 * rt + 4 * quad + r;
                        if (kp > q0 + qv) arg = -3.0e38f;
                    }
                    p[r] = fexp2(arg);
                }
                rl[ct] += (p[0] + p[1]) + (p[2] + p[3]);
                int g16 = 4 * kr + 2 * rt + (quad >> 1);
                uint2 pkk;
                pkk.x = pk2(p[0], p[1]);
                pkk.y = pk2(p[2], p[3]);
                *(uint2*)&lp[qv * 64 + (g16 ^ (qv & 7)) * 8 + (quad & 1) * 4] = pkk;
            }
        }
        __syncthreads();   // B2: P visible
        if (kt + 1 < KT) {  // prefetch next K/V into alt buffer; drains at next B1
            int k1 = k0 + 64;
            u16* nk = &lds[16384 + ((kt + 1) & 1) * 12288];
            int goff = tid, grow = goff >> 3, glog = (goff & 7) ^ (grow & 7);
            gload16(kbase + (size_t)(k1 + grow) * EE + glog * 8, (void*)&nk[goff * 8]);
#pragma unroll
            for (int i = 0; i < 2; i++) {
                int go = i * 512 + tid, gr = go >> 3, gl = (go & 7) ^ (gr & 7);
                gload16(vbase + (size_t)gr * SS + k1 + gl * 8, (void*)&nk[4096 + go * 8]);
            }
        }
        // ---- pass B: O += P * Vt ----
#pragma unroll
        for (int ks = 0; ks < 2; ks++) {
            bf16x8 vb[4];
#pragma unroll
            for (int ct = 0; ct < 4; ct++) {
                int nn = dc * 64 + ct * 16 + l15;
                vb[ct] = *(const bf16x8*)&lv[nn * 64 + ((((ks << 2) + quad) ^ (nn & 7))) * 8];
            }
#pragma unroll
            for (int rt = 0; rt < 4; rt++) {
                int m = qr * 64 + rt * 16 + l15;
                bf16x8 pa = *(const bf16x8*)&lp[m * 64 + ((((ks << 2) + quad) ^ (m & 7))) * 8];
#pragma unroll
                for (int ct = 0; ct < 4; ct++) o[rt][ct] = MFMA(pa, vb[ct], o[rt][ct]);
            }
        }
        __syncthreads();   // B1: pass B done (lp WAR) + prefetch landed (vmcnt drain)
    }
    // ---- denominator (lsum aliases lp; loop fully done with lp) ----
    if (tid < 256) lsum[tid] = 0.f;
    __syncthreads();
#pragma unroll
    for (int ct = 0; ct < 4; ct++) {
        float t = rl[ct];
        t += __shfl_xor(t, 16, 64);
        t += __shfl_xor(t, 32, 64);
        if (quad == 0) atomicAdd(&lsum[qc * 64 + ct * 16 + l15], t);
    }
    __syncthreads();
    // ---- epilogue ----
    float* obase = out + ((size_t)b * SS + q0) * DD + d0 + dc * 64;
#pragma unroll
    for (int rt = 0; rt < 4; rt++) {
#pragma unroll
        for (int r = 0; r < 4; r++) {
            int row = qr * 64 + rt * 16 + 4 * quad + r;
            float li = 1.0f / lsum[row];
#pragma unroll
            for (int ct = 0; ct < 4; ct++)
                obase[(size_t)row * DD + ct * 16 + l15] = o[rt][ct][r] * li;
        }
    }
}

extern "C" void kernel_launch(void* const* d_in, const int* in_sizes, int n_in,
                              void* d_out, int out_size, void* d_ws, size_t ws_size,
                              hipStream_t stream) {
    (void)in_sizes; (void)n_in; (void)out_size; (void)ws_size;
    const float* enc = (const float*)d_in[0];
    const float* wq = (const float*)d_in[1];
    const float* wk = (const float*)d_in[2];
    char* ws = (char*)d_ws;
    u16* qbf = (u16*)ws;                  // 2 MiB
    u16* kbf = (u16*)(ws + (2ull << 20)); // 2 MiB
    u16* vt  = (u16*)(ws + (4ull << 20)); // 32 MiB
    float* out = (float*)d_out;

    hipLaunchKernelGGL(k_proj, dim3(256), dim3(512), 0, stream, enc, wq, wk, qbf, kbf);
    hipLaunchKernelGGL(k_tcast, dim3(16, 64, 4), dim3(256), 0, stream, enc, vt);
    hipLaunchKernelGGL(k_attn, dim3(512), dim3(512), 0, stream, qbf, kbf, vt, out);
}

// Round 4
// 255.785 us; speedup vs baseline: 4.4630x; 4.4630x over previous
//
#include <hip/hip_runtime.h>

typedef __bf16 bf16;
typedef bf16 bf16x8 __attribute__((ext_vector_type(8)));
typedef float f32x4 __attribute__((ext_vector_type(4)));
typedef unsigned int u32;
typedef unsigned short u16;

#define BB 4
#define SS 4096
#define DD 1024
#define EE 64
static constexpr float SCALE2 = 0.18033688011112042f; // (1/8)*log2(e)
static constexpr float MFIX = 16.0f;                  // fixed softmax shift (log2 domain)

#define MFMA(a,b,c) __builtin_amdgcn_mfma_f32_16x16x32_bf16((a),(b),(c),0,0,0)

typedef __attribute__((address_space(3))) unsigned int lds_u32;
typedef const __attribute__((address_space(1))) unsigned int glb_u32;

static __device__ __forceinline__ void gload16(const void* g, void* l) {
    __builtin_amdgcn_global_load_lds((glb_u32*)g, (lds_u32*)l, 16, 0, 0);
}

static __device__ __forceinline__ u16 f2bf(float x) {
    union { float f; u32 u; } v; v.f = x;
    u32 r = v.u + 0x7FFFu + ((v.u >> 16) & 1u);
    return (u16)(r >> 16);
}
static __device__ __forceinline__ u32 pk2(float a, float b) {
    return (u32)f2bf(a) | ((u32)f2bf(b) << 16);
}
static __device__ __forceinline__ float fexp2(float x) {
    return __builtin_amdgcn_exp2f(x);
}

// ---------------- Kernel 1: Q&K projection GEMM, dual-output, m64 x n128, 256 blocks ----
// enc read ONCE (vs twice in R2/R3 split). W (512KB) is L2/LLC-resident across blocks.
__global__ __launch_bounds__(512, 4) void k_proj(const float* __restrict__ enc,
                                                 const float* __restrict__ wq,
                                                 const float* __restrict__ wk,
                                                 u16* __restrict__ qout,
                                                 u16* __restrict__ kout) {
    __shared__ __align__(16) u16 la[64 * 64];    // A: 64 rows x 64 k (bf16), swizzled
    __shared__ __align__(16) u16 lw[128 * 64];   // W: 128 rows (Q0-63|K64-127) x 64 k
    const int tid = threadIdx.x;
    const int m0 = blockIdx.x * 64;
    const int w = tid >> 6, lane = tid & 63, l15 = lane & 15, quad = lane >> 4;
    const int ari = tid >> 3, ag = tid & 7;            // A staging: 64 rows x 8 floats
    const int wri = tid >> 2, wg = (tid & 3) * 2;      // W staging: 128 rows x 16 floats
    const float* arow = enc + (size_t)(m0 + ari) * DD + ag * 8;
    const float* wrow = ((wri < 64) ? (wq + (size_t)wri * DD) : (wk + (size_t)(wri - 64) * DD)) + (tid & 3) * 16;

    float4 a0 = *(const float4*)(arow);
    float4 a1 = *(const float4*)(arow + 4);
    float4 b0 = *(const float4*)(wrow);
    float4 b1 = *(const float4*)(wrow + 4);
    float4 b2 = *(const float4*)(wrow + 8);
    float4 b3 = *(const float4*)(wrow + 12);

    f32x4 acc[4];
#pragma unroll
    for (int i = 0; i < 4; i++) acc[i] = f32x4{0.f, 0.f, 0.f, 0.f};

    for (int kk = 0; kk < DD; kk += 64) {
        uint4 pa, pw0, pw1;
        pa.x = pk2(a0.x, a0.y); pa.y = pk2(a0.z, a0.w);
        pa.z = pk2(a1.x, a1.y); pa.w = pk2(a1.z, a1.w);
        pw0.x = pk2(b0.x, b0.y); pw0.y = pk2(b0.z, b0.w);
        pw0.z = pk2(b1.x, b1.y); pw0.w = pk2(b1.z, b1.w);
        pw1.x = pk2(b2.x, b2.y); pw1.y = pk2(b2.z, b2.w);
        pw1.z = pk2(b3.x, b3.y); pw1.w = pk2(b3.z, b3.w);
        __syncthreads();   // prev iteration's fragment readers done
        *(uint4*)&la[ari * 64 + (ag ^ (ari & 7)) * 8] = pa;
        *(uint4*)&lw[wri * 64 + ((wg + 0) ^ (wri & 7)) * 8] = pw0;
        *(uint4*)&lw[wri * 64 + ((wg + 1) ^ (wri & 7)) * 8] = pw1;
        __syncthreads();
        if (kk + 64 < DD) {   // prefetch next tile behind MFMA
            a0 = *(const float4*)(arow + kk + 64);
            a1 = *(const float4*)(arow + kk + 68);
            b0 = *(const float4*)(wrow + kk + 64);
            b1 = *(const float4*)(wrow + kk + 68);
            b2 = *(const float4*)(wrow + kk + 72);
            b3 = *(const float4*)(wrow + kk + 76);
        }
        int m = 16 * (w & 3) + l15;
#pragma unroll
        for (int es = 0; es < 2; es++) {
            bf16x8 af = *(const bf16x8*)&la[m * 64 + ((((es << 2) + quad) ^ (m & 7))) * 8];
#pragma unroll
            for (int ct = 0; ct < 4; ct++) {
                int n = 64 * (w >> 2) + 16 * ct + l15;
                bf16x8 bf_ = *(const bf16x8*)&lw[n * 64 + ((((es << 2) + quad) ^ (n & 7))) * 8];
                acc[ct] = MFMA(af, bf_, acc[ct]);
            }
        }
    }
#pragma unroll
    for (int ct = 0; ct < 4; ct++) {
        int n = 64 * (w >> 2) + 16 * ct + l15;
        u16* dst = (n < 64) ? qout : kout;
        int col = n & 63;
#pragma unroll
        for (int r = 0; r < 4; r++) {
            int grow = m0 + 16 * (w & 3) + 4 * quad + r;
            dst[(size_t)grow * EE + col] = f2bf(acc[ct][r]);
        }
    }
}

// ---------------- Kernel 2: transpose-cast enc -> Vt[b][d][s] bf16 (conflict-free) ----
__global__ __launch_bounds__(256) void k_tcast(const float* __restrict__ enc, u16* __restrict__ vt) {
    __shared__ u32 lt2[32][67];
    const int tid = threadIdx.x;
    const int dt = blockIdx.x, st = blockIdx.y, b = blockIdx.z;
    const int srow = tid >> 2, d0 = (tid & 3) << 4;
    const float* src = enc + ((size_t)(b * SS + st * 64 + srow) * DD) + dt * 64 + d0;
    float4 f0 = ((const float4*)src)[0];
    float4 f1 = ((const float4*)src)[1];
    float4 f2 = ((const float4*)src)[2];
    float4 f3 = ((const float4*)src)[3];
    float v[16];
    v[0] = f0.x; v[1] = f0.y; v[2] = f0.z; v[3] = f0.w;
    v[4] = f1.x; v[5] = f1.y; v[6] = f1.z; v[7] = f1.w;
    v[8] = f2.x; v[9] = f2.y; v[10] = f2.z; v[11] = f2.w;
    v[12] = f3.x; v[13] = f3.y; v[14] = f3.z; v[15] = f3.w;
#pragma unroll
    for (int j = 0; j < 8; j++) lt2[(d0 >> 1) + j][srow] = pk2(v[2 * j], v[2 * j + 1]);
    __syncthreads();
    const int dp = tid >> 3, soct = tid & 7;
    u32 a[8];
#pragma unroll
    for (int j = 0; j < 8; j++) a[j] = lt2[dp][soct * 8 + j];
    uint4 r0, r1;
    r0.x = (a[0] & 0xffffu) | (a[1] << 16);
    r0.y = (a[2] & 0xffffu) | (a[3] << 16);
    r0.z = (a[4] & 0xffffu) | (a[5] << 16);
    r0.w = (a[6] & 0xffffu) | (a[7] << 16);
    r1.x = (a[0] >> 16) | (a[1] & 0xffff0000u);
    r1.y = (a[2] >> 16) | (a[3] & 0xffff0000u);
    r1.z = (a[4] >> 16) | (a[5] & 0xffff0000u);
    r1.w = (a[6] >> 16) | (a[7] & 0xffff0000u);
    u16* dst0 = vt + ((size_t)(b * DD + dt * 64 + 2 * dp) * SS) + st * 64 + soct * 8;
    *(uint4*)dst0 = r0;
    *(uint4*)(dst0 + SS) = r1;
}

// ---------------- Kernel 3: fused attention q128 x d256, paired q-tiles, dbuf --------
// LDS (u16 units): lp [0,8192) ; lsum (float[128]) at [8192,8448) ;
//                  K/V dbuf at 8448 + buf*20480  (K 64x64 = 4096, V 256x64 = 16384)
// Total 98816 B -> 1 block/CU. Grid = 256 blocks, each EXACTLY 66 k-iters (qt pair).
__global__ __launch_bounds__(512, 2) void k_attn(const u16* __restrict__ qg, const u16* __restrict__ kg,
                                                 const u16* __restrict__ vt, float* __restrict__ out) {
    __shared__ __align__(16) u16 lds[49408];
    u16* lp = lds;
    float* lsum = (float*)&lds[8192];
    const int tid = threadIdx.x;
    const int w = tid >> 6, lane = tid & 63, l15 = lane & 15, quad = lane >> 4;
    const int pr = blockIdx.x & 15, combo = blockIdx.x >> 4;
    const int ds = combo & 3, b = combo >> 2;
    const int d0 = ds * 256;
    const int kr = w & 1, qc = w >> 1;   // pass A: 2 k-halves x 4 q-slices(32)
    const int dc = w & 3, qr = w >> 2;   // pass B: 4 d-slices(64) x 2 q-halves(64)
    const u16* kbase = kg + (size_t)b * SS * EE;
    const u16* vbase = vt + ((size_t)b * DD + d0) * SS;

    for (int half = 0; half < 2; half++) {
        const int qt = half ? pr : (31 - pr);   // heavy tile first; pair sums to 66 iters
        const int q0 = qt * 128;
        const int KT = 2 * qt + 2;
        const u16* qbase = qg + ((size_t)b * SS + q0) * EE;
        __syncthreads();   // protect lsum/lp reuse across halves
        if (tid < 128) lsum[tid] = 0.f;
        // stage K/V tile 0 into buf0
        {
            int goff = tid, grow = goff >> 3, glog = (goff & 7) ^ (grow & 7);
            gload16(kbase + (size_t)grow * EE + glog * 8, (void*)&lds[8448 + goff * 8]);
#pragma unroll
            for (int i = 0; i < 4; i++) {
                int go = i * 512 + tid, gr = go >> 3, gl = (go & 7) ^ (gr & 7);
                gload16(vbase + (size_t)gr * SS + gl * 8, (void*)&lds[8448 + 4096 + go * 8]);
            }
        }
        // Q fragments straight from global (L2-hit), no LDS round trip
        bf16x8 qf[2][2];
#pragma unroll
        for (int ct = 0; ct < 2; ct++) {
            int qv = 32 * qc + 16 * ct + l15;
#pragma unroll
            for (int es = 0; es < 2; es++)
                qf[ct][es] = *(const bf16x8*)(qbase + (size_t)qv * EE + es * 32 + quad * 8);
        }
        f32x4 o[4][4];
#pragma unroll
        for (int i = 0; i < 4; i++)
#pragma unroll
            for (int j = 0; j < 4; j++) o[i][j] = f32x4{0.f, 0.f, 0.f, 0.f};
        float rl[2] = {0.f, 0.f};
        __syncthreads();   // staging drained, lsum zeros visible

        for (int kt = 0; kt < KT; kt++) {
            const int k0 = kt * 64;
            const u16* lk = &lds[8448 + (kt & 1) * 20480];
            const u16* lv = lk + 4096;
            const bool dg = (kt >= KT - 2);
            // ---- pass A: S^T (64k x 128q), exp2, P -> lp ----
#pragma unroll
            for (int rt = 0; rt < 2; rt++) {
                int m = 32 * kr + 16 * rt + l15;
                bf16x8 ka0 = *(const bf16x8*)&lk[m * 64 + ((quad ^ (m & 7))) * 8];
                bf16x8 ka1 = *(const bf16x8*)&lk[m * 64 + (((4 + quad) ^ (m & 7))) * 8];
#pragma unroll
                for (int ct = 0; ct < 2; ct++) {
                    f32x4 c = f32x4{0.f, 0.f, 0.f, 0.f};
                    c = MFMA(ka0, qf[ct][0], c);
                    c = MFMA(ka1, qf[ct][1], c);
                    int qv = 32 * qc + 16 * ct + l15;
                    float p[4];
#pragma unroll
                    for (int r = 0; r < 4; r++) {
                        float arg = __builtin_fmaf(c[r], SCALE2, -MFIX);
                        if (dg) {
                            int kp = k0 + 32 * kr + 16 * rt + 4 * quad + r;
                            if (kp > q0 + qv) arg = -3.0e38f;   // exp2 -> 0
                        }
                        p[r] = fexp2(arg);
                    }
                    rl[ct] += (p[0] + p[1]) + (p[2] + p[3]);
                    int g16 = 4 * kr + 2 * rt + (quad >> 1);
                    uint2 pkk;
                    pkk.x = pk2(p[0], p[1]);
                    pkk.y = pk2(p[2], p[3]);
                    *(uint2*)&lp[qv * 64 + (g16 ^ (qv & 7)) * 8 + (quad & 1) * 4] = pkk;
                }
            }
            __syncthreads();   // B2: P visible (no loads in flight -> cheap)
            if (kt + 1 < KT) { // prefetch next K/V into alt buffer; drains at B1
                int k1 = k0 + 64;
                u16* nb = &lds[8448 + ((kt + 1) & 1) * 20480];
                int goff = tid, grow = goff >> 3, glog = (goff & 7) ^ (grow & 7);
                gload16(kbase + (size_t)(k1 + grow) * EE + glog * 8, (void*)&nb[goff * 8]);
#pragma unroll
                for (int i = 0; i < 4; i++) {
                    int go = i * 512 + tid, gr = go >> 3, gl = (go & 7) ^ (gr & 7);
                    gload16(vbase + (size_t)gr * SS + k1 + gl * 8, (void*)&nb[4096 + go * 8]);
                }
            }
            // ---- pass B: O += P * Vt ----
#pragma unroll
            for (int ks = 0; ks < 2; ks++) {
                bf16x8 vb[4];
#pragma unroll
                for (int ct = 0; ct < 4; ct++) {
                    int n = 64 * dc + 16 * ct + l15;
                    vb[ct] = *(const bf16x8*)&lv[n * 64 + ((((ks << 2) + quad) ^ (n & 7))) * 8];
                }
#pragma unroll
                for (int rt = 0; rt < 4; rt++) {
                    int m = 64 * qr + 16 * rt + l15;
                    bf16x8 pa = *(const bf16x8*)&lp[m * 64 + ((((ks << 2) + quad) ^ (m & 7))) * 8];
#pragma unroll
                    for (int ct = 0; ct < 4; ct++) o[rt][ct] = MFMA(pa, vb[ct], o[rt][ct]);
                }
            }
            __syncthreads();   // B1: pass B done (lp WAR) + prefetch drained (vmcnt)
        }
        // ---- denominator ----
#pragma unroll
        for (int ct = 0; ct < 2; ct++) {
            float t = rl[ct];
            t += __shfl_xor(t, 16, 64);
            t += __shfl_xor(t, 32, 64);
            if (quad == 0) atomicAdd(&lsum[32 * qc + 16 * ct + l15], t);
        }
        __syncthreads();
        // ---- epilogue ----
        float* obase = out + ((size_t)b * SS + q0) * DD + d0 + dc * 64;
#pragma unroll
        for (int rt = 0; rt < 4; rt++) {
#pragma unroll
            for (int r = 0; r < 4; r++) {
                int row = 64 * qr + 16 * rt + 4 * quad + r;
                float li = 1.0f / lsum[row];
#pragma unroll
                for (int ct = 0; ct < 4; ct++)
                    obase[(size_t)row * DD + ct * 16 + l15] = o[rt][ct][r] * li;
            }
        }
    }
}

extern "C" void kernel_launch(void* const* d_in, const int* in_sizes, int n_in,
                              void* d_out, int out_size, void* d_ws, size_t ws_size,
                              hipStream_t stream) {
    (void)in_sizes; (void)n_in; (void)out_size; (void)ws_size;
    const float* enc = (const float*)d_in[0];
    const float* wq = (const float*)d_in[1];
    const float* wk = (const float*)d_in[2];
    char* ws = (char*)d_ws;
    u16* qbf = (u16*)ws;                  // 2 MiB
    u16* kbf = (u16*)(ws + (2ull << 20)); // 2 MiB
    u16* vt  = (u16*)(ws + (4ull << 20)); // 32 MiB
    float* out = (float*)d_out;

    hipLaunchKernelGGL(k_proj, dim3(256), dim3(512), 0, stream, enc, wq, wk, qbf, kbf);
    hipLaunchKernelGGL(k_tcast, dim3(16, 64, 4), dim3(256), 0, stream, enc, vt);
    hipLaunchKernelGGL(k_attn, dim3(256), dim3(512), 0, stream, qbf, kbf, vt, out);
}

// Round 5
// 243.982 us; speedup vs baseline: 4.6789x; 1.0484x over previous
//
#include <hip/hip_runtime.h>

typedef __bf16 bf16;
typedef bf16 bf16x8 __attribute__((ext_vector_type(8)));
typedef float f32x4 __attribute__((ext_vector_type(4)));
typedef unsigned int u32;
typedef unsigned short u16;

#define BB 4
#define SS 4096
#define DD 1024
#define EE 64
static constexpr float SCALE2 = 0.18033688011112042f; // (1/8)*log2(e)
static constexpr float MFIX = 16.0f;                  // fixed softmax shift (log2 domain)

#define MFMA(a,b,c) __builtin_amdgcn_mfma_f32_16x16x32_bf16((a),(b),(c),0,0,0)

typedef __attribute__((address_space(3))) unsigned int lds_u32;
typedef const __attribute__((address_space(1))) unsigned int glb_u32;

static __device__ __forceinline__ void gload16(const void* g, void* l) {
    __builtin_amdgcn_global_load_lds((glb_u32*)g, (lds_u32*)l, 16, 0, 0);
}

static __device__ __forceinline__ u16 f2bf(float x) {
    union { float f; u32 u; } v; v.f = x;
    u32 r = v.u + 0x7FFFu + ((v.u >> 16) & 1u);
    return (u16)(r >> 16);
}
static __device__ __forceinline__ u32 pk2(float a, float b) {
    return (u32)f2bf(a) | ((u32)f2bf(b) << 16);
}
static __device__ __forceinline__ float fexp2(float x) {
    return __builtin_amdgcn_exp2f(x);
}

// ---------------- Kernel 1: fused prep = {Q/K projection GEMM} + {enc->Vt transpose-cast}
// blocks [0,256): proj (m64 x n128, dual Q|K output). blocks [256,2304): tcast, 2 tiles each.
// Independent roles co-resident -> VALU-bound proj overlaps HBM-bound tcast.
__global__ __launch_bounds__(512, 4) void k_prep(const float* __restrict__ enc,
                                                 const float* __restrict__ wq,
                                                 const float* __restrict__ wk,
                                                 u16* __restrict__ qout,
                                                 u16* __restrict__ kout,
                                                 u16* __restrict__ vt) {
    __shared__ __align__(16) u16 sm[12288];   // 24 KB, overlaid between the two roles
    const int tid = threadIdx.x;
    if (blockIdx.x < 256) {
        // ================= proj =================
        u16* la = sm;            // A: 64 rows x 64 k (bf16), swizzled
        u16* lw = sm + 4096;     // W: 128 rows (Q0-63|K64-127) x 64 k
        const int m0 = blockIdx.x * 64;
        const int w = tid >> 6, lane = tid & 63, l15 = lane & 15, quad = lane >> 4;
        const int ari = tid >> 3, ag = tid & 7;         // A staging: 64 rows x 8 floats
        const int wri = tid >> 2, wg = (tid & 3) * 2;   // W staging: 128 rows x 16 floats
        const float* arow = enc + (size_t)(m0 + ari) * DD + ag * 8;
        const float* wrow = ((wri < 64) ? (wq + (size_t)wri * DD) : (wk + (size_t)(wri - 64) * DD)) + (tid & 3) * 16;

        float4 a0 = *(const float4*)(arow);
        float4 a1 = *(const float4*)(arow + 4);
        float4 b0 = *(const float4*)(wrow);
        float4 b1 = *(const float4*)(wrow + 4);
        float4 b2 = *(const float4*)(wrow + 8);
        float4 b3 = *(const float4*)(wrow + 12);

        f32x4 acc[4];
#pragma unroll
        for (int i = 0; i < 4; i++) acc[i] = f32x4{0.f, 0.f, 0.f, 0.f};

        for (int kk = 0; kk < DD; kk += 64) {
            uint4 pa, pw0, pw1;
            pa.x = pk2(a0.x, a0.y); pa.y = pk2(a0.z, a0.w);
            pa.z = pk2(a1.x, a1.y); pa.w = pk2(a1.z, a1.w);
            pw0.x = pk2(b0.x, b0.y); pw0.y = pk2(b0.z, b0.w);
            pw0.z = pk2(b1.x, b1.y); pw0.w = pk2(b1.z, b1.w);
            pw1.x = pk2(b2.x, b2.y); pw1.y = pk2(b2.z, b2.w);
            pw1.z = pk2(b3.x, b3.y); pw1.w = pk2(b3.z, b3.w);
            __syncthreads();
            *(uint4*)&la[ari * 64 + (ag ^ (ari & 7)) * 8] = pa;
            *(uint4*)&lw[wri * 64 + ((wg + 0) ^ (wri & 7)) * 8] = pw0;
            *(uint4*)&lw[wri * 64 + ((wg + 1) ^ (wri & 7)) * 8] = pw1;
            __syncthreads();
            if (kk + 64 < DD) {
                a0 = *(const float4*)(arow + kk + 64);
                a1 = *(const float4*)(arow + kk + 68);
                b0 = *(const float4*)(wrow + kk + 64);
                b1 = *(const float4*)(wrow + kk + 68);
                b2 = *(const float4*)(wrow + kk + 72);
                b3 = *(const float4*)(wrow + kk + 76);
            }
            int m = 16 * (w & 3) + l15;
#pragma unroll
            for (int es = 0; es < 2; es++) {
                bf16x8 af = *(const bf16x8*)&la[m * 64 + ((((es << 2) + quad) ^ (m & 7))) * 8];
#pragma unroll
                for (int ct = 0; ct < 4; ct++) {
                    int n = 64 * (w >> 2) + 16 * ct + l15;
                    bf16x8 bf_ = *(const bf16x8*)&lw[n * 64 + ((((es << 2) + quad) ^ (n & 7))) * 8];
                    acc[ct] = MFMA(af, bf_, acc[ct]);
                }
            }
        }
#pragma unroll
        for (int ct = 0; ct < 4; ct++) {
            int n = 64 * (w >> 2) + 16 * ct + l15;
            u16* dst = (n < 64) ? qout : kout;
            int col = n & 63;
#pragma unroll
            for (int r = 0; r < 4; r++) {
                int grow = m0 + 16 * (w & 3) + 4 * quad + r;
                dst[(size_t)grow * EE + col] = f2bf(acc[ct][r]);
            }
        }
    } else {
        // ================= tcast (two 64x64 tiles per block) =================
        u32* lt2 = (u32*)sm + (tid >> 8) * 2144;   // [32][67] per sub-tile
        const int t = tid & 255;
        const int tc = blockIdx.x - 256;
        const int dt = tc & 15, stp = (tc >> 4) & 31, b = tc >> 9;
        const int st = stp * 2 + (tid >> 8);
        const int srow = t >> 2, d0 = (t & 3) << 4;
        const float* src = enc + ((size_t)(b * SS + st * 64 + srow) * DD) + dt * 64 + d0;
        float4 f0 = ((const float4*)src)[0];
        float4 f1 = ((const float4*)src)[1];
        float4 f2 = ((const float4*)src)[2];
        float4 f3 = ((const float4*)src)[3];
        float v[16];
        v[0] = f0.x; v[1] = f0.y; v[2] = f0.z; v[3] = f0.w;
        v[4] = f1.x; v[5] = f1.y; v[6] = f1.z; v[7] = f1.w;
        v[8] = f2.x; v[9] = f2.y; v[10] = f2.z; v[11] = f2.w;
        v[12] = f3.x; v[13] = f3.y; v[14] = f3.z; v[15] = f3.w;
#pragma unroll
        for (int j = 0; j < 8; j++) lt2[((d0 >> 1) + j) * 67 + srow] = pk2(v[2 * j], v[2 * j + 1]);
        __syncthreads();
        const int dp = t >> 3, soct = t & 7;
        u32 a[8];
#pragma unroll
        for (int j = 0; j < 8; j++) a[j] = lt2[dp * 67 + soct * 8 + j];
        uint4 r0, r1;
        r0.x = (a[0] & 0xffffu) | (a[1] << 16);
        r0.y = (a[2] & 0xffffu) | (a[3] << 16);
        r0.z = (a[4] & 0xffffu) | (a[5] << 16);
        r0.w = (a[6] & 0xffffu) | (a[7] << 16);
        r1.x = (a[0] >> 16) | (a[1] & 0xffff0000u);
        r1.y = (a[2] >> 16) | (a[3] & 0xffff0000u);
        r1.z = (a[4] >> 16) | (a[5] & 0xffff0000u);
        r1.w = (a[6] >> 16) | (a[7] & 0xffff0000u);
        u16* dst0 = vt + ((size_t)(b * DD + dt * 64 + 2 * dp) * SS) + st * 64 + soct * 8;
        *(uint4*)dst0 = r0;
        *(uint4*)(dst0 + SS) = r1;
    }
}

// ---------------- Kernel 2: fused attention q128 x d256, paired q-tiles ---------------
// Register-staged K/V prefetch: global->VGPR at iter top (pass A covers latency),
// ds_write->alt buffer after the P barrier. No global_load_lds inside the loop, so
// pass B's ds_reads never eat the conservative vmcnt(0) LDS-DMA alias drain.
// LDS: lp [0,8192) u16 ; lsum float[128] at [8192] ; K/V dbuf at 8448 + buf*20480.
__global__ __launch_bounds__(512, 2) void k_attn(const u16* __restrict__ qg, const u16* __restrict__ kg,
                                                 const u16* __restrict__ vt, float* __restrict__ out) {
    __shared__ __align__(16) u16 lds[49408];   // 98816 B -> 1 block/CU
    u16* lp = lds;
    float* lsum = (float*)&lds[8192];
    const int tid = threadIdx.x;
    const int w = tid >> 6, lane = tid & 63, l15 = lane & 15, quad = lane >> 4;
    const int pr = blockIdx.x & 15, combo = blockIdx.x >> 4;
    const int ds = combo & 3, b = combo >> 2;
    const int d0 = ds * 256;
    const int kr = w & 1, qc = w >> 1;   // pass A: 2 k-halves x 4 q-slices(32)
    const int dc = w & 3, qr = w >> 2;   // pass B: 4 d-slices(64) x 2 q-halves(64)
    const u16* kbase = kg + (size_t)b * SS * EE;
    const u16* vbase = vt + ((size_t)b * DD + d0) * SS;

    // per-thread staging source pointers (swizzled-granule pattern, loop-invariant part)
    const int kgrow = tid >> 3, kglog = (tid & 7) ^ (kgrow & 7);
    const u16* kptr = kbase + (size_t)kgrow * EE + kglog * 8;
    const u16* vptr0; const u16* vptr1; const u16* vptr2; const u16* vptr3;
    {
        int go0 = 0 * 512 + tid, gr0 = go0 >> 3, gl0 = (go0 & 7) ^ (gr0 & 7);
        int go1 = 1 * 512 + tid, gr1 = go1 >> 3, gl1 = (go1 & 7) ^ (gr1 & 7);
        int go2 = 2 * 512 + tid, gr2 = go2 >> 3, gl2 = (go2 & 7) ^ (gr2 & 7);
        int go3 = 3 * 512 + tid, gr3 = go3 >> 3, gl3 = (go3 & 7) ^ (gr3 & 7);
        vptr0 = vbase + (size_t)gr0 * SS + gl0 * 8;
        vptr1 = vbase + (size_t)gr1 * SS + gl1 * 8;
        vptr2 = vbase + (size_t)gr2 * SS + gl2 * 8;
        vptr3 = vbase + (size_t)gr3 * SS + gl3 * 8;
    }

    for (int half = 0; half < 2; half++) {
        const int qt = half ? pr : (31 - pr);   // heavy tile first; pair sums to 66 iters
        const int q0 = qt * 128;
        const int KT = 2 * qt + 2;
        const u16* qbase = qg + ((size_t)b * SS + q0) * EE;
        __syncthreads();   // protect lsum/lp/buf reuse across halves
        if (tid < 128) lsum[tid] = 0.f;
        // stage K/V tile 0 into buf0 (prologue only: the one vmcnt(0) drain per half)
        {
            int goff = tid, grow = goff >> 3, glog = (goff & 7) ^ (grow & 7);
            gload16(kbase + (size_t)grow * EE + glog * 8, (void*)&lds[8448 + goff * 8]);
#pragma unroll
            for (int i = 0; i < 4; i++) {
                int go = i * 512 + tid, gr = go >> 3, gl = (go & 7) ^ (gr & 7);
                gload16(vbase + (size_t)gr * SS + gl * 8, (void*)&lds[8448 + 4096 + go * 8]);
            }
        }
        // Q fragments straight from global (L2-hit), no LDS round trip
        bf16x8 qf[2][2];
#pragma unroll
        for (int ct = 0; ct < 2; ct++) {
            int qv = 32 * qc + 16 * ct + l15;
#pragma unroll
            for (int es = 0; es < 2; es++)
                qf[ct][es] = *(const bf16x8*)(qbase + (size_t)qv * EE + es * 32 + quad * 8);
        }
        f32x4 o[4][4];
#pragma unroll
        for (int i = 0; i < 4; i++)
#pragma unroll
            for (int j = 0; j < 4; j++) o[i][j] = f32x4{0.f, 0.f, 0.f, 0.f};
        float rl[2] = {0.f, 0.f};
        __syncthreads();   // prologue staging drained, lsum zeros visible

        for (int kt = 0; kt < KT; kt++) {
            const int k0 = kt * 64;
            const u16* lk = &lds[8448 + (kt & 1) * 20480];
            const u16* lv = lk + 4096;
            const bool dg = (kt >= KT - 2);
            const bool pf = (kt + 1 < KT);
            // ---- issue next tile's global loads into registers (latency covered by pass A)
            uint4 gk, gv0, gv1, gv2, gv3;
            if (pf) {
                const int k1 = k0 + 64;
                gk  = *(const uint4*)(kptr + (size_t)k1 * EE);
                gv0 = *(const uint4*)(vptr0 + k1);
                gv1 = *(const uint4*)(vptr1 + k1);
                gv2 = *(const uint4*)(vptr2 + k1);
                gv3 = *(const uint4*)(vptr3 + k1);
            }
            // ---- pass A: S^T (64k x 128q), exp2, P -> lp ----
#pragma unroll
            for (int rt = 0; rt < 2; rt++) {
                int m = 32 * kr + 16 * rt + l15;
                bf16x8 ka0 = *(const bf16x8*)&lk[m * 64 + ((quad ^ (m & 7))) * 8];
                bf16x8 ka1 = *(const bf16x8*)&lk[m * 64 + (((4 + quad) ^ (m & 7))) * 8];
#pragma unroll
                for (int ct = 0; ct < 2; ct++) {
                    f32x4 c = f32x4{0.f, 0.f, 0.f, 0.f};
                    c = MFMA(ka0, qf[ct][0], c);
                    c = MFMA(ka1, qf[ct][1], c);
                    int qv = 32 * qc + 16 * ct + l15;
                    float p[4];
#pragma unroll
                    for (int r = 0; r < 4; r++) {
                        float arg = __builtin_fmaf(c[r], SCALE2, -MFIX);
                        if (dg) {
                            int kp = k0 + 32 * kr + 16 * rt + 4 * quad + r;
                            if (kp > q0 + qv) arg = -3.0e38f;   // exp2 -> 0
                        }
                        p[r] = fexp2(arg);
                    }
                    rl[ct] += (p[0] + p[1]) + (p[2] + p[3]);
                    int g16 = 4 * kr + 2 * rt + (quad >> 1);
                    uint2 pkk;
                    pkk.x = pk2(p[0], p[1]);
                    pkk.y = pk2(p[2], p[3]);
                    *(uint2*)&lp[qv * 64 + (g16 ^ (qv & 7)) * 8 + (quad & 1) * 4] = pkk;
                }
            }
            __syncthreads();   // B2: P visible
            // ---- commit prefetch regs into alt buffer (precise per-reg vmcnt waits) ----
            if (pf) {
                u16* nb = &lds[8448 + ((kt + 1) & 1) * 20480];
                *(uint4*)&nb[tid * 8] = gk;
                *(uint4*)&nb[4096 + (0 * 512 + tid) * 8] = gv0;
                *(uint4*)&nb[4096 + (1 * 512 + tid) * 8] = gv1;
                *(uint4*)&nb[4096 + (2 * 512 + tid) * 8] = gv2;
                *(uint4*)&nb[4096 + (3 * 512 + tid) * 8] = gv3;
            }
            // ---- pass B: O += P * Vt (reads current buffer only -> no vmcnt stall) ----
#pragma unroll
            for (int ks = 0; ks < 2; ks++) {
                bf16x8 vb[4];
#pragma unroll
                for (int ct = 0; ct < 4; ct++) {
                    int n = 64 * dc + 16 * ct + l15;
                    vb[ct] = *(const bf16x8*)&lv[n * 64 + ((((ks << 2) + quad) ^ (n & 7))) * 8];
                }
#pragma unroll
                for (int rt = 0; rt < 4; rt++) {
                    int m = 64 * qr + 16 * rt + l15;
                    bf16x8 pa = *(const bf16x8*)&lp[m * 64 + ((((ks << 2) + quad) ^ (m & 7))) * 8];
#pragma unroll
                    for (int ct = 0; ct < 4; ct++) o[rt][ct] = MFMA(pa, vb[ct], o[rt][ct]);
                }
            }
            __syncthreads();   // B1: pass B done (lp WAR) + staged writes visible
        }
        // ---- denominator ----
#pragma unroll
        for (int ct = 0; ct < 2; ct++) {
            float t = rl[ct];
            t += __shfl_xor(t, 16, 64);
            t += __shfl_xor(t, 32, 64);
            if (quad == 0) atomicAdd(&lsum[32 * qc + 16 * ct + l15], t);
        }
        __syncthreads();
        // ---- epilogue ----
        float* obase = out + ((size_t)b * SS + q0) * DD + d0 + dc * 64;
#pragma unroll
        for (int rt = 0; rt < 4; rt++) {
#pragma unroll
            for (int r = 0; r < 4; r++) {
                int row = 64 * qr + 16 * rt + 4 * quad + r;
                float li = 1.0f / lsum[row];
#pragma unroll
                for (int ct = 0; ct < 4; ct++)
                    obase[(size_t)row * DD + ct * 16 + l15] = o[rt][ct][r] * li;
            }
        }
    }
}

extern "C" void kernel_launch(void* const* d_in, const int* in_sizes, int n_in,
                              void* d_out, int out_size, void* d_ws, size_t ws_size,
                              hipStream_t stream) {
    (void)in_sizes; (void)n_in; (void)out_size; (void)ws_size;
    const float* enc = (const float*)d_in[0];
    const float* wq = (const float*)d_in[1];
    const float* wk = (const float*)d_in[2];
    char* ws = (char*)d_ws;
    u16* qbf = (u16*)ws;                  // 2 MiB
    u16* kbf = (u16*)(ws + (2ull << 20)); // 2 MiB
    u16* vt  = (u16*)(ws + (4ull << 20)); // 32 MiB
    float* out = (float*)d_out;

    hipLaunchKernelGGL(k_prep, dim3(2304), dim3(512), 0, stream, enc, wq, wk, qbf, kbf, vt);
    hipLaunchKernelGGL(k_attn, dim3(256), dim3(512), 0, stream, qbf, kbf, vt, out);
}

// Round 6
// 236.767 us; speedup vs baseline: 4.8215x; 1.0305x over previous
//
#include <hip/hip_runtime.h>

typedef __bf16 bf16;
typedef bf16 bf16x2 __attribute__((ext_vector_type(2)));
typedef bf16 bf16x8 __attribute__((ext_vector_type(8)));
typedef float f32x4 __attribute__((ext_vector_type(4)));
typedef unsigned int u32;
typedef unsigned short u16;

#define BB 4
#define SS 4096
#define DD 1024
#define EE 64
static constexpr float SCALE2 = 0.18033688011112042f; // (1/8)*log2(e)
static constexpr float MFIX = 16.0f;                  // fixed softmax shift (log2 domain)

#define MFMA(a,b,c) __builtin_amdgcn_mfma_f32_16x16x32_bf16((a),(b),(c),0,0,0)

typedef __attribute__((address_space(3))) unsigned int lds_u32;
typedef const __attribute__((address_space(1))) unsigned int glb_u32;

static __device__ __forceinline__ void gload16(const void* g, void* l) {
    __builtin_amdgcn_global_load_lds((glb_u32*)g, (lds_u32*)l, 16, 0, 0);
}

static __device__ __forceinline__ u16 f2bf(float x) {
    union { bf16 h; u16 u; } v; v.h = (bf16)x;
    return v.u;
}
static __device__ __forceinline__ u32 pk2(float a, float b) {
    bf16x2 t; t[0] = (bf16)a; t[1] = (bf16)b;
    return __builtin_bit_cast(u32, t);
}
static __device__ __forceinline__ float fexp2(float x) {
    return __builtin_amdgcn_exp2f(x);
}

// ---------------- Kernel 1: fused prep = {Q/K projection GEMM} + {enc->Vt transpose-cast}
__global__ __launch_bounds__(512, 4) void k_prep(const float* __restrict__ enc,
                                                 const float* __restrict__ wq,
                                                 const float* __restrict__ wk,
                                                 u16* __restrict__ qout,
                                                 u16* __restrict__ kout,
                                                 u16* __restrict__ vt) {
    __shared__ __align__(16) u16 sm[12288];   // 24 KB, overlaid between the two roles
    const int tid = threadIdx.x;
    if (blockIdx.x < 256) {
        // ================= proj =================
        u16* la = sm;            // A: 64 rows x 64 k (bf16), swizzled
        u16* lw = sm + 4096;     // W: 128 rows (Q0-63|K64-127) x 64 k
        const int m0 = blockIdx.x * 64;
        const int w = tid >> 6, lane = tid & 63, l15 = lane & 15, quad = lane >> 4;
        const int ari = tid >> 3, ag = tid & 7;
        const int wri = tid >> 2, wg = (tid & 3) * 2;
        const float* arow = enc + (size_t)(m0 + ari) * DD + ag * 8;
        const float* wrow = ((wri < 64) ? (wq + (size_t)wri * DD) : (wk + (size_t)(wri - 64) * DD)) + (tid & 3) * 16;

        float4 a0 = *(const float4*)(arow);
        float4 a1 = *(const float4*)(arow + 4);
        float4 b0 = *(const float4*)(wrow);
        float4 b1 = *(const float4*)(wrow + 4);
        float4 b2 = *(const float4*)(wrow + 8);
        float4 b3 = *(const float4*)(wrow + 12);

        f32x4 acc[4];
#pragma unroll
        for (int i = 0; i < 4; i++) acc[i] = f32x4{0.f, 0.f, 0.f, 0.f};

        for (int kk = 0; kk < DD; kk += 64) {
            uint4 pa, pw0, pw1;
            pa.x = pk2(a0.x, a0.y); pa.y = pk2(a0.z, a0.w);
            pa.z = pk2(a1.x, a1.y); pa.w = pk2(a1.z, a1.w);
            pw0.x = pk2(b0.x, b0.y); pw0.y = pk2(b0.z, b0.w);
            pw0.z = pk2(b1.x, b1.y); pw0.w = pk2(b1.z, b1.w);
            pw1.x = pk2(b2.x, b2.y); pw1.y = pk2(b2.z, b2.w);
            pw1.z = pk2(b3.x, b3.y); pw1.w = pk2(b3.z, b3.w);
            __syncthreads();
            *(uint4*)&la[ari * 64 + (ag ^ (ari & 7)) * 8] = pa;
            *(uint4*)&lw[wri * 64 + ((wg + 0) ^ (wri & 7)) * 8] = pw0;
            *(uint4*)&lw[wri * 64 + ((wg + 1) ^ (wri & 7)) * 8] = pw1;
            __syncthreads();
            if (kk + 64 < DD) {
                a0 = *(const float4*)(arow + kk + 64);
                a1 = *(const float4*)(arow + kk + 68);
                b0 = *(const float4*)(wrow + kk + 64);
                b1 = *(const float4*)(wrow + kk + 68);
                b2 = *(const float4*)(wrow + kk + 72);
                b3 = *(const float4*)(wrow + kk + 76);
            }
            int m = 16 * (w & 3) + l15;
#pragma unroll
            for (int es = 0; es < 2; es++) {
                bf16x8 af = *(const bf16x8*)&la[m * 64 + ((((es << 2) + quad) ^ (m & 7))) * 8];
#pragma unroll
                for (int ct = 0; ct < 4; ct++) {
                    int n = 64 * (w >> 2) + 16 * ct + l15;
                    bf16x8 bf_ = *(const bf16x8*)&lw[n * 64 + ((((es << 2) + quad) ^ (n & 7))) * 8];
                    acc[ct] = MFMA(af, bf_, acc[ct]);
                }
            }
        }
#pragma unroll
        for (int ct = 0; ct < 4; ct++) {
            int n = 64 * (w >> 2) + 16 * ct + l15;
            u16* dst = (n < 64) ? qout : kout;
            int col = n & 63;
#pragma unroll
            for (int r = 0; r < 4; r++) {
                int grow = m0 + 16 * (w & 3) + 4 * quad + r;
                dst[(size_t)grow * EE + col] = f2bf(acc[ct][r]);
            }
        }
    } else {
        // ================= tcast (two 64x64 tiles per block) =================
        u32* lt2 = (u32*)sm + (tid >> 8) * 2144;
        const int t = tid & 255;
        const int tc = blockIdx.x - 256;
        const int dt = tc & 15, stp = (tc >> 4) & 31, b = tc >> 9;
        const int st = stp * 2 + (tid >> 8);
        const int srow = t >> 2, d0 = (t & 3) << 4;
        const float* src = enc + ((size_t)(b * SS + st * 64 + srow) * DD) + dt * 64 + d0;
        float4 f0 = ((const float4*)src)[0];
        float4 f1 = ((const float4*)src)[1];
        float4 f2 = ((const float4*)src)[2];
        float4 f3 = ((const float4*)src)[3];
        float v[16];
        v[0] = f0.x; v[1] = f0.y; v[2] = f0.z; v[3] = f0.w;
        v[4] = f1.x; v[5] = f1.y; v[6] = f1.z; v[7] = f1.w;
        v[8] = f2.x; v[9] = f2.y; v[10] = f2.z; v[11] = f2.w;
        v[12] = f3.x; v[13] = f3.y; v[14] = f3.z; v[15] = f3.w;
#pragma unroll
        for (int j = 0; j < 8; j++) lt2[((d0 >> 1) + j) * 67 + srow] = pk2(v[2 * j], v[2 * j + 1]);
        __syncthreads();
        const int dp = t >> 3, soct = t & 7;
        u32 a[8];
#pragma unroll
        for (int j = 0; j < 8; j++) a[j] = lt2[dp * 67 + soct * 8 + j];
        uint4 r0, r1;
        r0.x = (a[0] & 0xffffu) | (a[1] << 16);
        r0.y = (a[2] & 0xffffu) | (a[3] << 16);
        r0.z = (a[4] & 0xffffu) | (a[5] << 16);
        r0.w = (a[6] & 0xffffu) | (a[7] << 16);
        r1.x = (a[0] >> 16) | (a[1] & 0xffff0000u);
        r1.y = (a[2] >> 16) | (a[3] & 0xffff0000u);
        r1.z = (a[4] >> 16) | (a[5] & 0xffff0000u);
        r1.w = (a[6] >> 16) | (a[7] & 0xffff0000u);
        u16* dst0 = vt + ((size_t)(b * DD + dt * 64 + 2 * dp) * SS) + st * 64 + soct * 8;
        *(uint4*)dst0 = r0;
        *(uint4*)(dst0 + SS) = r1;
    }
}

// ---------------- Kernel 2: fused attention q128 x d256, MERGED-PHASE pipeline --------
// Phase p (one barrier each): commit V(p); issue loads for tile p+1 (K->LDS-DMA alt slot,
// V->regs); pass A(p) [S^T+exp2 -> lp[p&1]]; pass B(p-1) [O += P*V from lp/lv[(p-1)&1]].
// A's VALU/exp2 and B's MFMA now share each phase -> pipes overlap instead of serialize.
// LDS (u16): lp[2] @0/8192 ; lsum @16384 ; lk[2] @16640/20736 ; lv[2] @24832/41216.
__global__ __launch_bounds__(512, 2) void k_attn(const u16* __restrict__ qg, const u16* __restrict__ kg,
                                                 const u16* __restrict__ vt, float* __restrict__ out) {
    __shared__ __align__(16) u16 lds[57600];   // 115200 B -> 1 block/CU
    float* lsum = (float*)&lds[16384];
    const int tid = threadIdx.x;
    const int w = tid >> 6, lane = tid & 63, l15 = lane & 15, quad = lane >> 4;
    const int pr = blockIdx.x & 15, combo = blockIdx.x >> 4;
    const int ds = combo & 3, b = combo >> 2;
    const int d0 = ds * 256;
    const int kr = w & 1, qc = w >> 1;   // pass A: 2 k-halves x 4 q-slices(32)
    const int dc = w & 3, qr = w >> 2;   // pass B: 4 d-slices(64) x 2 q-halves(64)
    const u16* kbase = kg + (size_t)b * SS * EE;
    const u16* vbase = vt + ((size_t)b * DD + d0) * SS;

    const int kgrow = tid >> 3, kglog = (tid & 7) ^ (kgrow & 7);
    const u16* kptr = kbase + (size_t)kgrow * EE + kglog * 8;
    const u16 *vptr0, *vptr1, *vptr2, *vptr3;
    {
        int go0 = 0 * 512 + tid, gr0 = go0 >> 3, gl0 = (go0 & 7) ^ (gr0 & 7);
        int go1 = 1 * 512 + tid, gr1 = go1 >> 3, gl1 = (go1 & 7) ^ (gr1 & 7);
        int go2 = 2 * 512 + tid, gr2 = go2 >> 3, gl2 = (go2 & 7) ^ (gr2 & 7);
        int go3 = 3 * 512 + tid, gr3 = go3 >> 3, gl3 = (go3 & 7) ^ (gr3 & 7);
        vptr0 = vbase + (size_t)gr0 * SS + gl0 * 8;
        vptr1 = vbase + (size_t)gr1 * SS + gl1 * 8;
        vptr2 = vbase + (size_t)gr2 * SS + gl2 * 8;
        vptr3 = vbase + (size_t)gr3 * SS + gl3 * 8;
    }

    for (int half = 0; half < 2; half++) {
        const int qt = half ? pr : (31 - pr);   // heavy tile first; pair sums to 66 iters
        const int q0 = qt * 128;
        const int KT = 2 * qt + 2;
        const u16* qbase = qg + ((size_t)b * SS + q0) * EE;
        __syncthreads();   // prior half fully done with all LDS regions
        if (tid < 128) lsum[tid] = 0.f;
        // prologue: K(0)->lk[0], V(0)->lv[0] via LDS-DMA (drained at the barrier below)
        gload16(kptr, (void*)&lds[16640 + tid * 8]);
        gload16(vptr0, (void*)&lds[24832 + (0 * 512 + tid) * 8]);
        gload16(vptr1, (void*)&lds[24832 + (1 * 512 + tid) * 8]);
        gload16(vptr2, (void*)&lds[24832 + (2 * 512 + tid) * 8]);
        gload16(vptr3, (void*)&lds[24832 + (3 * 512 + tid) * 8]);
        // Q fragments straight from global (L2-hit), no LDS round trip
        bf16x8 qf[2][2];
#pragma unroll
        for (int ct = 0; ct < 2; ct++) {
            int qv = 32 * qc + 16 * ct + l15;
#pragma unroll
            for (int es = 0; es < 2; es++)
                qf[ct][es] = *(const bf16x8*)(qbase + (size_t)qv * EE + es * 32 + quad * 8);
        }
        f32x4 o[4][4];
#pragma unroll
        for (int i = 0; i < 4; i++)
#pragma unroll
            for (int j = 0; j < 4; j++) o[i][j] = f32x4{0.f, 0.f, 0.f, 0.f};
        float rl[2] = {0.f, 0.f};
        uint4 gv0, gv1, gv2, gv3;
        __syncthreads();   // prologue staging drained, lsum zeros visible

        for (int p = 0; p <= KT; p++) {
            // ---- commit V(p) (regs loaded at phase p-1) into lv[p&1] ----
            if (p >= 1 && p < KT) {
                u16* nv = &lds[24832 + (p & 1) * 16384];
                *(uint4*)&nv[(0 * 512 + tid) * 8] = gv0;
                *(uint4*)&nv[(1 * 512 + tid) * 8] = gv1;
                *(uint4*)&nv[(2 * 512 + tid) * 8] = gv2;
                *(uint4*)&nv[(3 * 512 + tid) * 8] = gv3;
            }
            // ---- issue loads for tile p+1: K via LDS-DMA to alt slot, V into regs ----
            if (p + 1 < KT) {
                const int k1 = (p + 1) * 64;
                gload16(kptr + (size_t)k1 * EE, (void*)&lds[16640 + ((p + 1) & 1) * 4096 + tid * 8]);
                gv0 = *(const uint4*)(vptr0 + k1);
                gv1 = *(const uint4*)(vptr1 + k1);
                gv2 = *(const uint4*)(vptr2 + k1);
                gv3 = *(const uint4*)(vptr3 + k1);
            }
            // ---- pass A(p): S^T (64k x 128q), exp2, P -> lp[p&1] ----
            if (p < KT) {
                const int k0 = p * 64;
                const u16* lk = &lds[16640 + (p & 1) * 4096];
                u16* lpw = &lds[(p & 1) * 8192];
                const bool dg = (p >= KT - 2);
#pragma unroll
                for (int rt = 0; rt < 2; rt++) {
                    int m = 32 * kr + 16 * rt + l15;
                    bf16x8 ka0 = *(const bf16x8*)&lk[m * 64 + ((quad ^ (m & 7))) * 8];
                    bf16x8 ka1 = *(const bf16x8*)&lk[m * 64 + (((4 + quad) ^ (m & 7))) * 8];
#pragma unroll
                    for (int ct = 0; ct < 2; ct++) {
                        f32x4 c = f32x4{0.f, 0.f, 0.f, 0.f};
                        c = MFMA(ka0, qf[ct][0], c);
                        c = MFMA(ka1, qf[ct][1], c);
                        int qv = 32 * qc + 16 * ct + l15;
                        float pv[4];
#pragma unroll
                        for (int r = 0; r < 4; r++) {
                            float arg = __builtin_fmaf(c[r], SCALE2, -MFIX);
                            if (dg) {
                                int kp = k0 + 32 * kr + 16 * rt + 4 * quad + r;
                                if (kp > q0 + qv) arg = -3.0e38f;   // exp2 -> 0
                            }
                            pv[r] = fexp2(arg);
                        }
                        rl[ct] += (pv[0] + pv[1]) + (pv[2] + pv[3]);
                        int g16 = 4 * kr + 2 * rt + (quad >> 1);
                        uint2 pkk;
                        pkk.x = pk2(pv[0], pv[1]);
                        pkk.y = pk2(pv[2], pv[3]);
                        *(uint2*)&lpw[qv * 64 + (g16 ^ (qv & 7)) * 8 + (quad & 1) * 4] = pkk;
                    }
                }
            }
            // ---- pass B(p-1): O += P * Vt from lp/lv[(p-1)&1] ----
            if (p >= 1) {
                const u16* lv = &lds[24832 + ((p - 1) & 1) * 16384];
                const u16* lpr = &lds[((p - 1) & 1) * 8192];
#pragma unroll
                for (int ks = 0; ks < 2; ks++) {
                    bf16x8 vb[4];
#pragma unroll
                    for (int ct = 0; ct < 4; ct++) {
                        int n = 64 * dc + 16 * ct + l15;
                        vb[ct] = *(const bf16x8*)&lv[n * 64 + ((((ks << 2) + quad) ^ (n & 7))) * 8];
                    }
#pragma unroll
                    for (int rt = 0; rt < 4; rt++) {
                        int m = 64 * qr + 16 * rt + l15;
                        bf16x8 pa = *(const bf16x8*)&lpr[m * 64 + ((((ks << 2) + quad) ^ (m & 7))) * 8];
#pragma unroll
                        for (int ct = 0; ct < 4; ct++) o[rt][ct] = MFMA(pa, vb[ct], o[rt][ct]);
                    }
                }
            }
            __syncthreads();   // single barrier per phase
        }
        // ---- denominator ----
#pragma unroll
        for (int ct = 0; ct < 2; ct++) {
            float t = rl[ct];
            t += __shfl_xor(t, 16, 64);
            t += __shfl_xor(t, 32, 64);
            if (quad == 0) atomicAdd(&lsum[32 * qc + 16 * ct + l15], t);
        }
        __syncthreads();
        // ---- epilogue ----
        float* obase = out + ((size_t)b * SS + q0) * DD + d0 + dc * 64;
#pragma unroll
        for (int rt = 0; rt < 4; rt++) {
#pragma unroll
            for (int r = 0; r < 4; r++) {
                int row = 64 * qr + 16 * rt + 4 * quad + r;
                float li = 1.0f / lsum[row];
#pragma unroll
                for (int ct = 0; ct < 4; ct++)
                    obase[(size_t)row * DD + ct * 16 + l15] = o[rt][ct][r] * li;
            }
        }
    }
}

extern "C" void kernel_launch(void* const* d_in, const int* in_sizes, int n_in,
                              void* d_out, int out_size, void* d_ws, size_t ws_size,
                              hipStream_t stream) {
    (void)in_sizes; (void)n_in; (void)out_size; (void)ws_size;
    const float* enc = (const float*)d_in[0];
    const float* wq = (const float*)d_in[1];
    const float* wk = (const float*)d_in[2];
    char* ws = (char*)d_ws;
    u16* qbf = (u16*)ws;                  // 2 MiB
    u16* kbf = (u16*)(ws + (2ull << 20)); // 2 MiB
    u16* vt  = (u16*)(ws + (4ull << 20)); // 32 MiB
    float* out = (float*)d_out;

    hipLaunchKernelGGL(k_prep, dim3(2304), dim3(512), 0, stream, enc, wq, wk, qbf, kbf, vt);
    hipLaunchKernelGGL(k_attn, dim3(256), dim3(512), 0, stream, qbf, kbf, vt, out);
}